// Round 12
// baseline (111.087 us; speedup 1.0000x reference)
//
#include <hip/hip_runtime.h>
#include <hip/hip_bf16.h>

typedef __attribute__((ext_vector_type(8))) short short8v;
typedef __attribute__((ext_vector_type(4))) float f32x4;
typedef __attribute__((ext_vector_type(2))) float v2f;

#define Q4SCALE 0.375f
#define Q4INV   2.6666667f

__device__ __forceinline__ unsigned short f2b(float f) {
    union { float f; unsigned int u; } v; v.f = f;
    unsigned int r = (v.u + 0x7fffu + ((v.u >> 16) & 1u)) >> 16;
    return (unsigned short)r;
}
__device__ __forceinline__ unsigned int pack2(float lo, float hi) {
    return (unsigned int)f2b(lo) | ((unsigned int)f2b(hi) << 16);
}
__device__ __forceinline__ void unpk_fp8x4(unsigned int u, float* o) {
    v2f lo = __builtin_amdgcn_cvt_pk_f32_fp8(u, false);
    v2f hi = __builtin_amdgcn_cvt_pk_f32_fp8(u, true);
    o[0] = lo[0]; o[1] = lo[1]; o[2] = hi[0]; o[3] = hi[1];
}
__device__ __forceinline__ unsigned int q4(float v) {
    int q = __float2int_rn(v * Q4INV);
    q = q < -8 ? -8 : (q > 7 ? 7 : q);
    return (unsigned int)(q & 0xF);
}
__device__ __forceinline__ void unpk_i4x8(unsigned int u, float* o) {
    #pragma unroll
    for (int i = 0; i < 8; ++i) {
        int sv = ((int)(u << (28 - 4 * i))) >> 28;
        o[i] = (float)sv * Q4SCALE;
    }
}

// ---------------------------------------------------------------------------
// K0: pack Wl|Wr into bf16 MFMA-B-fragment order Whf, bh = bl|br,
//     zero zbuf[0..nz) (denom/csrc/S).
// ---------------------------------------------------------------------------
__global__ __launch_bounds__(256) void prep(
    const float* __restrict__ Wl, const float* __restrict__ bl,
    const float* __restrict__ Wr, const float* __restrict__ br,
    unsigned short* __restrict__ Whf, float* __restrict__ bh,
    float* __restrict__ zbuf, int nz)
{
    const int idx    = blockIdx.x * 256 + threadIdx.x;
    const int stride = gridDim.x * 256;

    for (int i = idx; i < 32768; i += stride) {
        int j   = i & 7;
        int l   = (i >> 3) & 63;
        int nfg = (i >> 9) & 15;
        int ks  = i >> 13;
        int k = ks * 32 + (l >> 4) * 8 + j;
        int c = nfg * 16 + (l & 15);
        float v = (c < 128) ? Wl[k * 128 + c] : Wr[k * 128 + (c - 128)];
        Whf[i] = f2b(v);
    }
    if (idx < 256) bh[idx] = (idx < 128) ? bl[idx] : br[idx - 128];
    for (int i = idx; i < nz; i += stride) zbuf[i] = 0.f;
}

// ---------------------------------------------------------------------------
// K1: MFMA GEMM -> XLq (fp8, for wsum) + XL4/XR4 (int4 64B rows, for logits).
// ---------------------------------------------------------------------------
#define GBM 64
__global__ __launch_bounds__(256) void gemm_mfma(
    const float* __restrict__ x, const unsigned short* __restrict__ Whf,
    const float* __restrict__ bh,
    unsigned char* __restrict__ XLq,
    unsigned char* __restrict__ XL4, unsigned char* __restrict__ XR4,
    int n)
{
    __shared__ unsigned short xs[GBM * 128];     // 16 KB A-tile (swizzled)
    __shared__ unsigned char  lbuf[GBM][256];    // 16 KB fp8 C-tile (L|R)

    const int tid = threadIdx.x;
    const int w   = tid >> 6;
    const int l   = tid & 63;
    const int lr  = l & 15;
    const int lk  = l >> 4;

    short8v B[4][4];
    #pragma unroll
    for (int ks = 0; ks < 4; ++ks)
        #pragma unroll
        for (int nf = 0; nf < 4; ++nf)
            B[ks][nf] = *(const short8v*)&Whf[(((ks * 16 + (w * 4 + nf)) * 64 + l) << 3)];

    float biasv[4];
    #pragma unroll
    for (int nf = 0; nf < 4; ++nf) biasv[nf] = bh[w * 64 + nf * 16 + lr];

    const int sr  = tid >> 2;
    const int sc0 = (tid & 3) * 32;
    const int swz = (sr & 7) << 4;
    const int row0 = blockIdx.x * GBM;

    {
        const int grow = row0 + sr;
        if (grow < n) {
            const float4* src = (const float4*)&x[(size_t)grow * 128 + sc0];
            #pragma unroll
            for (int i = 0; i < 8; ++i) {
                float4 v = src[i];
                uint2 p; p.x = pack2(v.x, v.y); p.y = pack2(v.z, v.w);
                int byte = (sc0 + i * 4) * 2;
                *(uint2*)((char*)xs + sr * 256 + (byte ^ swz)) = p;
            }
        } else {
            uint2 p{0, 0};
            #pragma unroll
            for (int i = 0; i < 8; ++i) {
                int byte = (sc0 + i * 4) * 2;
                *(uint2*)((char*)xs + sr * 256 + (byte ^ swz)) = p;
            }
        }
    }
    __syncthreads();

    f32x4 acc[4][4];
    #pragma unroll
    for (int mf = 0; mf < 4; ++mf)
        #pragma unroll
        for (int nf = 0; nf < 4; ++nf)
            acc[mf][nf] = f32x4{0.f, 0.f, 0.f, 0.f};

    #pragma unroll
    for (int ks = 0; ks < 4; ++ks) {
        short8v A[4];
        #pragma unroll
        for (int mf = 0; mf < 4; ++mf) {
            int rr = mf * 16 + lr;
            int byte = (ks * 32 + lk * 8) * 2;
            A[mf] = *(short8v*)((char*)xs + rr * 256 + (byte ^ ((rr & 7) << 4)));
        }
        #pragma unroll
        for (int mf = 0; mf < 4; ++mf)
            #pragma unroll
            for (int nf = 0; nf < 4; ++nf)
                acc[mf][nf] = __builtin_amdgcn_mfma_f32_16x16x32_bf16(
                    A[mf], B[ks][nf], acc[mf][nf], 0, 0, 0);
    }

    // epilogue: bias + fp8 into LDS (full 256 cols)
    #pragma unroll
    for (int mf = 0; mf < 4; ++mf) {
        #pragma unroll
        for (int nf = 0; nf < 4; ++nf) {
            const int ocol = w * 64 + nf * 16 + lr;
            #pragma unroll
            for (int j = 0; j < 4; ++j) {
                unsigned int u = __builtin_amdgcn_cvt_pk_fp8_f32(
                    acc[mf][nf][j] + biasv[nf], 0.f, 0u, false);
                lbuf[mf * 16 + lk * 4 + j][ocol] = (unsigned char)u;
            }
        }
    }
    __syncthreads();

    // fp8 XLq stores (cols 0..127): 512 chunks of 16B
    #pragma unroll
    for (int k = 0; k < 2; ++k) {
        const int ch  = k * 256 + tid;
        const int row = ch >> 3;
        const int seg = ch & 7;
        const int grow = row0 + row;
        if (grow < n) {
            uint4 v = *(const uint4*)&lbuf[row][seg * 16];
            *(uint4*)&XLq[(size_t)grow * 128 + seg * 16] = v;
        }
    }

    // int4 XL4/XR4 stores: 512 chunks; each chunk = 32 fp8 -> 16 nibble-bytes
    #pragma unroll
    for (int k = 0; k < 2; ++k) {
        const int ch  = k * 256 + tid;
        const int row = ch >> 3;
        const int seg = ch & 7;          // 0..3 -> L, 4..7 -> R
        const int grow = row0 + row;
        if (grow < n) {
            const int cbase = (seg & 3) * 32 + (seg >> 2) * 128;
            uint4 u0 = *(const uint4*)&lbuf[row][cbase];
            uint4 u1 = *(const uint4*)&lbuf[row][cbase + 16];
            float f[32];
            unpk_fp8x4(u0.x, f + 0);  unpk_fp8x4(u0.y, f + 4);
            unpk_fp8x4(u0.z, f + 8);  unpk_fp8x4(u0.w, f + 12);
            unpk_fp8x4(u1.x, f + 16); unpk_fp8x4(u1.y, f + 20);
            unpk_fp8x4(u1.z, f + 24); unpk_fp8x4(u1.w, f + 28);
            unsigned int wds[4];
            #pragma unroll
            for (int t4 = 0; t4 < 4; ++t4) {
                unsigned int a4 = 0;
                #pragma unroll
                for (int b = 0; b < 4; ++b) {
                    int c = t4 * 8 + b * 2;
                    a4 |= (q4(f[c]) | (q4(f[c + 1]) << 4)) << (8 * b);
                }
                wds[t4] = a4;
            }
            uint4 st{wds[0], wds[1], wds[2], wds[3]};
            unsigned char* dst = (seg < 4)
                ? &XL4[(size_t)grow * 64 + (seg & 3) * 16]
                : &XR4[(size_t)grow * 64 + (seg & 3) * 16];
            *(uint4*)dst = st;
        }
    }
}

// ---------------------------------------------------------------------------
// K2: per-edge logits + denom atomics.  8 lanes/edge; int4 rows = ONE 64B
// cache line per gathered row (halves line-granular L3 traffic vs fp8).
// ---------------------------------------------------------------------------
__global__ __launch_bounds__(256) void edge_logits(
    const unsigned char* __restrict__ XL4, const unsigned char* __restrict__ XR4,
    const int* __restrict__ ei, const float* __restrict__ att,
    float* __restrict__ wbuf, float* __restrict__ denom,
    int nE, int nTot)
{
    const int sub = threadIdx.x & 7;            // 16 features each
    const int grp = threadIdx.x >> 3;           // 0..31
    const int estep = gridDim.x * 32;

    const float4* ap = (const float4*)&att[sub * 16];
    const float4 a0 = ap[0], a1 = ap[1], a2 = ap[2], a3 = ap[3];

    for (int e = blockIdx.x * 32 + grp; e < nTot; e += estep) {
        int src, dst;
        if (e < nE) { src = ei[e]; dst = ei[nE + e]; }
        else        { src = dst = e - nE; }

        uint2 ul = *(const uint2*)&XL4[(size_t)src * 64 + sub * 8];
        uint2 ur = *(const uint2*)&XR4[(size_t)dst * 64 + sub * 8];

        float fl[16], fr[16];
        unpk_i4x8(ul.x, fl + 0); unpk_i4x8(ul.y, fl + 8);
        unpk_i4x8(ur.x, fr + 0); unpk_i4x8(ur.y, fr + 8);

        const float4 av[4] = {a0, a1, a2, a3};
        float p = 0.f;
        #pragma unroll
        for (int q = 0; q < 4; ++q) {
            float s0 = fl[q*4+0] + fr[q*4+0];
            float s1 = fl[q*4+1] + fr[q*4+1];
            float s2 = fl[q*4+2] + fr[q*4+2];
            float s3 = fl[q*4+3] + fr[q*4+3];
            s0 = s0 > 0.f ? s0 : 0.2f*s0;  s1 = s1 > 0.f ? s1 : 0.2f*s1;
            s2 = s2 > 0.f ? s2 : 0.2f*s2;  s3 = s3 > 0.f ? s3 : 0.2f*s3;
            p += s0*av[q].x + s1*av[q].y + s2*av[q].z + s3*av[q].w;
        }

        #pragma unroll
        for (int m = 4; m >= 1; m >>= 1) p += __shfl_xor(p, m);

        if (sub == 0) {
            float wv = __expf(p);   // logits O(1); softmax shift-invariant
            wbuf[e] = wv;
            atomicAdd(&denom[dst], wv);
        }
    }
}

// ---------------------------------------------------------------------------
// K3: c[src] += w[e] * rcp(denom[dst])   (grid-stride)
// ---------------------------------------------------------------------------
__global__ __launch_bounds__(256) void edge_coeff(
    const int* __restrict__ ei, const float* __restrict__ wbuf,
    const float* __restrict__ denom, float* __restrict__ csrc,
    int nE, int nTot)
{
    const int step = gridDim.x * 256;
    for (int e = blockIdx.x * 256 + threadIdx.x; e < nTot; e += step) {
        int src, dst;
        if (e < nE) { src = ei[e]; dst = ei[nE + e]; }
        else        { src = dst = e - nE; }
        atomicAdd(&csrc[src], wbuf[e] * __builtin_amdgcn_rcpf(denom[dst]));
    }
}

// ---------------------------------------------------------------------------
// K4: S = sum_j c[j] * xl[j]   (dense fp8 stream — accuracy path)
// ---------------------------------------------------------------------------
__global__ __launch_bounds__(256) void wsum(
    const unsigned char* __restrict__ XLq, const float* __restrict__ csrc,
    float* __restrict__ S, int n)
{
    const int sub = threadIdx.x & 7;
    const int grp = threadIdx.x >> 3;
    const int strd = gridDim.x * 32;

    float acc[16];
    #pragma unroll
    for (int k = 0; k < 16; ++k) acc[k] = 0.f;

    for (int j = blockIdx.x * 32 + grp; j < n; j += strd) {
        float cj = csrc[j];
        uint4 u = *(const uint4*)&XLq[(size_t)j * 128 + sub * 16];
        float f[16];
        unpk_fp8x4(u.x, f + 0); unpk_fp8x4(u.y, f + 4);
        unpk_fp8x4(u.z, f + 8); unpk_fp8x4(u.w, f + 12);
        #pragma unroll
        for (int k = 0; k < 16; ++k) acc[k] += cj * f[k];
    }

    __shared__ float sb[32][128];
    #pragma unroll
    for (int k = 0; k < 16; k += 4)
        *(float4*)&sb[grp][sub * 16 + k] = make_float4(acc[k], acc[k+1], acc[k+2], acc[k+3]);
    __syncthreads();

    if (threadIdx.x < 128) {
        float t = 0.f;
        #pragma unroll
        for (int g = 0; g < 32; ++g) t += sb[g][threadIdx.x];
        atomicAdd(&S[threadIdx.x], t);
    }
}

// ---------------------------------------------------------------------------
// K5: g = BN_affine(S/n + bias1); out = softmax(g @ Wc + bc)
// ---------------------------------------------------------------------------
__global__ __launch_bounds__(128) void finalize(
    const float* __restrict__ S, const float* __restrict__ bias1,
    const float* __restrict__ gamma, const float* __restrict__ beta,
    const float* __restrict__ mean, const float* __restrict__ var,
    const float* __restrict__ Wc, const float* __restrict__ bc,
    float* __restrict__ out, int n)
{
    __shared__ float g[128];
    __shared__ float lg[5];
    const int t = threadIdx.x;

    float gv = (S[t] / (float)n + bias1[t] - mean[t])
             * rsqrtf(var[t] + 1e-5f) * gamma[t] + beta[t];
    g[t] = gv;
    __syncthreads();

    if (t < 5) {
        float acc = bc[t];
        #pragma unroll 16
        for (int d = 0; d < 128; ++d) acc += g[d] * Wc[d * 5 + t];
        lg[t] = acc;
    }
    __syncthreads();

    if (t == 0) {
        float m = lg[0];
        #pragma unroll
        for (int i = 1; i < 5; ++i) m = fmaxf(m, lg[i]);
        float ex[5]; float sum = 0.f;
        #pragma unroll
        for (int i = 0; i < 5; ++i) { ex[i] = expf(lg[i] - m); sum += ex[i]; }
        #pragma unroll
        for (int i = 0; i < 5; ++i) out[i] = ex[i] / sum;
    }
}

// ---------------------------------------------------------------------------
extern "C" void kernel_launch(void* const* d_in, const int* in_sizes, int n_in,
                              void* d_out, int out_size, void* d_ws, size_t ws_size,
                              hipStream_t stream)
{
    const float* x     = (const float*)d_in[0];
    const int*   ei    = (const int*)  d_in[1];
    const float* Wl    = (const float*)d_in[2];
    const float* bl    = (const float*)d_in[3];
    const float* Wr    = (const float*)d_in[4];
    const float* br    = (const float*)d_in[5];
    const float* att   = (const float*)d_in[6];
    const float* bias1 = (const float*)d_in[7];
    const float* gamma = (const float*)d_in[8];
    const float* beta  = (const float*)d_in[9];
    const float* mean  = (const float*)d_in[10];
    const float* var   = (const float*)d_in[11];
    const float* Wc    = (const float*)d_in[12];
    const float* bc    = (const float*)d_in[13];

    const int n    = in_sizes[0] / 128;
    const int nE   = in_sizes[1] / 2;
    const int nTot = nE + n;

    unsigned char* XLq = (unsigned char*)d_ws;                       // n*128 fp8
    unsigned char* XL4 = XLq + (size_t)n * 128;                      // n*64 int4
    unsigned char* XR4 = XL4 + (size_t)n * 64;                       // n*64 int4
    unsigned short* Whf = (unsigned short*)(XR4 + (size_t)n * 64);   // 32768 bf16
    float* bh    = (float*)(Whf + 32768);                            // 256
    float* wbuf  = bh + 256;                                         // nTot
    float* denom = wbuf + nTot;                                      // n   } zeroed
    float* csrc  = denom + n;                                        // n   } by prep
    float* S     = csrc + n;                                         // 128 }
    const int nz = 2 * n + 128;

    prep<<<512, 256, 0, stream>>>(Wl, bl, Wr, br, Whf, bh, denom, nz);

    const int ntiles = (n + GBM - 1) / GBM;
    gemm_mfma<<<ntiles, 256, 0, stream>>>(x, Whf, bh, XLq, XL4, XR4, n);

    edge_logits<<<2048, 256, 0, stream>>>(XL4, XR4, ei, att, wbuf, denom, nE, nTot);

    edge_coeff<<<2048, 256, 0, stream>>>(ei, wbuf, denom, csrc, nE, nTot);

    wsum<<<512, 256, 0, stream>>>(XLq, csrc, S, n);

    finalize<<<1, 128, 0, stream>>>(S, bias1, gamma, beta, mean, var, Wc, bc,
                                    (float*)d_out, n);
}

// Round 13
// 107.099 us; speedup vs baseline: 1.0372x; 1.0372x over previous
//
#include <hip/hip_runtime.h>
#include <hip/hip_bf16.h>

typedef __attribute__((ext_vector_type(8))) short short8v;
typedef __attribute__((ext_vector_type(4))) float f32x4;
typedef __attribute__((ext_vector_type(2))) float v2f;

__device__ __forceinline__ unsigned short f2b(float f) {
    union { float f; unsigned int u; } v; v.f = f;
    unsigned int r = (v.u + 0x7fffu + ((v.u >> 16) & 1u)) >> 16;
    return (unsigned short)r;
}
__device__ __forceinline__ unsigned int pack2(float lo, float hi) {
    return (unsigned int)f2b(lo) | ((unsigned int)f2b(hi) << 16);
}
__device__ __forceinline__ void unpk_fp8x4(unsigned int u, float* o) {
    v2f lo = __builtin_amdgcn_cvt_pk_f32_fp8(u, false);
    v2f hi = __builtin_amdgcn_cvt_pk_f32_fp8(u, true);
    o[0] = lo[0]; o[1] = lo[1]; o[2] = hi[0]; o[3] = hi[1];
}

// ---------------------------------------------------------------------------
// K0: pack Wl|Wr into bf16 MFMA-B-fragment order Whf, bh = bl|br,
//     zero zbuf[0..nz) (denom/csrc/S/counter).
// ---------------------------------------------------------------------------
__global__ __launch_bounds__(256) void prep(
    const float* __restrict__ Wl, const float* __restrict__ bl,
    const float* __restrict__ Wr, const float* __restrict__ br,
    unsigned short* __restrict__ Whf, float* __restrict__ bh,
    float* __restrict__ zbuf, int nz)
{
    const int idx    = blockIdx.x * 256 + threadIdx.x;
    const int stride = gridDim.x * 256;

    for (int i = idx; i < 32768; i += stride) {
        int j   = i & 7;
        int l   = (i >> 3) & 63;
        int nfg = (i >> 9) & 15;
        int ks  = i >> 13;
        int k = ks * 32 + (l >> 4) * 8 + j;
        int c = nfg * 16 + (l & 15);
        float v = (c < 128) ? Wl[k * 128 + c] : Wr[k * 128 + (c - 128)];
        Whf[i] = f2b(v);
    }
    if (idx < 256) bh[idx] = (idx < 128) ? bl[idx] : br[idx - 128];
    for (int i = idx; i < nz; i += stride) zbuf[i] = 0.f;
}

// ---------------------------------------------------------------------------
// K1: [XLq|XRq] = fp8(x @ [Wl|Wr] + [bl|br]) via bf16 MFMA.  (R5/R9-exact)
// ---------------------------------------------------------------------------
#define GBM 64
__global__ __launch_bounds__(256) void gemm_mfma(
    const float* __restrict__ x, const unsigned short* __restrict__ Whf,
    const float* __restrict__ bh,
    unsigned char* __restrict__ XLq, unsigned char* __restrict__ XRq,
    int n)
{
    __shared__ unsigned short xs[GBM * 128];     // 16 KB A-tile (swizzled)
    __shared__ unsigned char  lbuf[GBM][256];    // 16 KB fp8 C-tile

    const int tid = threadIdx.x;
    const int w   = tid >> 6;
    const int l   = tid & 63;
    const int lr  = l & 15;
    const int lk  = l >> 4;

    short8v B[4][4];
    #pragma unroll
    for (int ks = 0; ks < 4; ++ks)
        #pragma unroll
        for (int nf = 0; nf < 4; ++nf)
            B[ks][nf] = *(const short8v*)&Whf[(((ks * 16 + (w * 4 + nf)) * 64 + l) << 3)];

    float biasv[4];
    #pragma unroll
    for (int nf = 0; nf < 4; ++nf) biasv[nf] = bh[w * 64 + nf * 16 + lr];

    const int sr  = tid >> 2;
    const int sc0 = (tid & 3) * 32;
    const int swz = (sr & 7) << 4;
    const int row0 = blockIdx.x * GBM;

    {
        const int grow = row0 + sr;
        if (grow < n) {
            const float4* src = (const float4*)&x[(size_t)grow * 128 + sc0];
            #pragma unroll
            for (int i = 0; i < 8; ++i) {
                float4 v = src[i];
                uint2 p; p.x = pack2(v.x, v.y); p.y = pack2(v.z, v.w);
                int byte = (sc0 + i * 4) * 2;
                *(uint2*)((char*)xs + sr * 256 + (byte ^ swz)) = p;
            }
        } else {
            uint2 p{0, 0};
            #pragma unroll
            for (int i = 0; i < 8; ++i) {
                int byte = (sc0 + i * 4) * 2;
                *(uint2*)((char*)xs + sr * 256 + (byte ^ swz)) = p;
            }
        }
    }
    __syncthreads();

    f32x4 acc[4][4];
    #pragma unroll
    for (int mf = 0; mf < 4; ++mf)
        #pragma unroll
        for (int nf = 0; nf < 4; ++nf)
            acc[mf][nf] = f32x4{0.f, 0.f, 0.f, 0.f};

    #pragma unroll
    for (int ks = 0; ks < 4; ++ks) {
        short8v A[4];
        #pragma unroll
        for (int mf = 0; mf < 4; ++mf) {
            int rr = mf * 16 + lr;
            int byte = (ks * 32 + lk * 8) * 2;
            A[mf] = *(short8v*)((char*)xs + rr * 256 + (byte ^ ((rr & 7) << 4)));
        }
        #pragma unroll
        for (int mf = 0; mf < 4; ++mf)
            #pragma unroll
            for (int nf = 0; nf < 4; ++nf)
                acc[mf][nf] = __builtin_amdgcn_mfma_f32_16x16x32_bf16(
                    A[mf], B[ks][nf], acc[mf][nf], 0, 0, 0);
    }

    #pragma unroll
    for (int mf = 0; mf < 4; ++mf) {
        #pragma unroll
        for (int nf = 0; nf < 4; ++nf) {
            const int ocol = w * 64 + nf * 16 + lr;
            #pragma unroll
            for (int j = 0; j < 4; ++j) {
                unsigned int u = __builtin_amdgcn_cvt_pk_fp8_f32(
                    acc[mf][nf][j] + biasv[nf], 0.f, 0u, false);
                lbuf[mf * 16 + lk * 4 + j][ocol] = (unsigned char)u;
            }
        }
    }
    __syncthreads();

    #pragma unroll
    for (int k = 0; k < 4; ++k) {
        const int ch  = k * 256 + tid;
        const int row = ch >> 4;
        const int seg = ch & 15;
        const int grow = row0 + row;
        if (grow < n) {
            uint4 v = *(const uint4*)&lbuf[row][seg * 16];
            if (seg < 8) *(uint4*)&XLq[(size_t)grow * 128 + seg * 16] = v;
            else         *(uint4*)&XRq[(size_t)grow * 128 + (seg - 8) * 16] = v;
        }
    }
}

// ---------------------------------------------------------------------------
// K2: per-edge logits + denom atomics.  8 lanes/edge, fp8, grid-stride.
// ---------------------------------------------------------------------------
__global__ __launch_bounds__(256) void edge_logits(
    const unsigned char* __restrict__ XLq, const unsigned char* __restrict__ XRq,
    const int* __restrict__ ei, const float* __restrict__ att,
    float* __restrict__ wbuf, float* __restrict__ denom,
    int nE, int nTot)
{
    const int sub = threadIdx.x & 7;
    const int grp = threadIdx.x >> 3;          // 0..31
    const int estep = gridDim.x * 32;

    const float4* ap = (const float4*)&att[sub * 16];
    const float4 a0 = ap[0], a1 = ap[1], a2 = ap[2], a3 = ap[3];

    for (int e = blockIdx.x * 32 + grp; e < nTot; e += estep) {
        int src, dst;
        if (e < nE) { src = ei[e]; dst = ei[nE + e]; }
        else        { src = dst = e - nE; }

        uint4 ul = *(const uint4*)&XLq[(size_t)src * 128 + sub * 16];
        uint4 ur = *(const uint4*)&XRq[(size_t)dst * 128 + sub * 16];

        float fl[16], fr[16];
        unpk_fp8x4(ul.x, fl + 0); unpk_fp8x4(ul.y, fl + 4);
        unpk_fp8x4(ul.z, fl + 8); unpk_fp8x4(ul.w, fl + 12);
        unpk_fp8x4(ur.x, fr + 0); unpk_fp8x4(ur.y, fr + 4);
        unpk_fp8x4(ur.z, fr + 8); unpk_fp8x4(ur.w, fr + 12);

        const float4 av[4] = {a0, a1, a2, a3};
        float p = 0.f;
        #pragma unroll
        for (int q = 0; q < 4; ++q) {
            float s0 = fl[q*4+0] + fr[q*4+0];
            float s1 = fl[q*4+1] + fr[q*4+1];
            float s2 = fl[q*4+2] + fr[q*4+2];
            float s3 = fl[q*4+3] + fr[q*4+3];
            s0 = s0 > 0.f ? s0 : 0.2f*s0;  s1 = s1 > 0.f ? s1 : 0.2f*s1;
            s2 = s2 > 0.f ? s2 : 0.2f*s2;  s3 = s3 > 0.f ? s3 : 0.2f*s3;
            p += s0*av[q].x + s1*av[q].y + s2*av[q].z + s3*av[q].w;
        }

        #pragma unroll
        for (int m = 4; m >= 1; m >>= 1) p += __shfl_xor(p, m);

        if (sub == 0) {
            float wv = __expf(p);   // logits O(1); softmax shift-invariant
            wbuf[e] = wv;
            atomicAdd(&denom[dst], wv);
        }
    }
}

// ---------------------------------------------------------------------------
// K3: c[src] += w[e] * rcp(denom[dst])   (grid-stride)
// ---------------------------------------------------------------------------
__global__ __launch_bounds__(256) void edge_coeff(
    const int* __restrict__ ei, const float* __restrict__ wbuf,
    const float* __restrict__ denom, float* __restrict__ csrc,
    int nE, int nTot)
{
    const int step = gridDim.x * 256;
    for (int e = blockIdx.x * 256 + threadIdx.x; e < nTot; e += step) {
        int src, dst;
        if (e < nE) { src = ei[e]; dst = ei[nE + e]; }
        else        { src = dst = e - nE; }
        atomicAdd(&csrc[src], wbuf[e] * __builtin_amdgcn_rcpf(denom[dst]));
    }
}

// ---------------------------------------------------------------------------
// K4: S = sum_j c[j]*xl[j]; last block (syncthreads-ordered counter, NO
//     threadfence) does BN + classifier + softmax and writes d_out.
// ---------------------------------------------------------------------------
__global__ __launch_bounds__(256) void wsum_fin(
    const unsigned char* __restrict__ XLq, const float* __restrict__ csrc,
    float* __restrict__ S, unsigned int* __restrict__ counter, int n,
    const float* __restrict__ bias1,
    const float* __restrict__ gamma, const float* __restrict__ beta,
    const float* __restrict__ mean, const float* __restrict__ var,
    const float* __restrict__ Wc, const float* __restrict__ bc,
    float* __restrict__ out)
{
    const int sub = threadIdx.x & 7;       // 16 features each
    const int grp = threadIdx.x >> 3;      // 32 nodes per block slice
    const int strd = gridDim.x * 32;

    float acc[16];
    #pragma unroll
    for (int k = 0; k < 16; ++k) acc[k] = 0.f;

    for (int j = blockIdx.x * 32 + grp; j < n; j += strd) {
        float cj = csrc[j];
        uint4 u = *(const uint4*)&XLq[(size_t)j * 128 + sub * 16];
        float f[16];
        unpk_fp8x4(u.x, f + 0); unpk_fp8x4(u.y, f + 4);
        unpk_fp8x4(u.z, f + 8); unpk_fp8x4(u.w, f + 12);
        #pragma unroll
        for (int k = 0; k < 16; ++k) acc[k] += cj * f[k];
    }

    __shared__ float sb[32][128];
    #pragma unroll
    for (int k = 0; k < 16; k += 4)
        *(float4*)&sb[grp][sub * 16 + k] = make_float4(acc[k], acc[k+1], acc[k+2], acc[k+3]);
    __syncthreads();

    if (threadIdx.x < 128) {
        float t = 0.f;
        #pragma unroll
        for (int g = 0; g < 32; ++g) t += sb[g][threadIdx.x];
        atomicAdd(&S[threadIdx.x], t);
    }

    // ordering: __syncthreads waits vmcnt(0) on every thread -> all S-atomics
    // of this block are globally performed before thread 0 bumps the counter.
    __syncthreads();
    __shared__ unsigned int isLast;
    if (threadIdx.x == 0) {
        unsigned int old = atomicAdd(counter, 1u);
        isLast = (old == (unsigned int)gridDim.x - 1u) ? 1u : 0u;
    }
    __syncthreads();
    if (!isLast) return;

    __shared__ float gbuf[128];
    __shared__ float lg[5];
    const int t = threadIdx.x;
    if (t < 128) {
        float sv = atomicAdd(&S[t], 0.f);   // coherent read of accumulated S
        gbuf[t] = (sv / (float)n + bias1[t] - mean[t])
                * rsqrtf(var[t] + 1e-5f) * gamma[t] + beta[t];
    }
    __syncthreads();
    if (t < 5) {
        float a = bc[t];
        #pragma unroll 16
        for (int d = 0; d < 128; ++d) a += gbuf[d] * Wc[d * 5 + t];
        lg[t] = a;
    }
    __syncthreads();
    if (t == 0) {
        float m = lg[0];
        #pragma unroll
        for (int i = 1; i < 5; ++i) m = fmaxf(m, lg[i]);
        float ex[5]; float sum = 0.f;
        #pragma unroll
        for (int i = 0; i < 5; ++i) { ex[i] = expf(lg[i] - m); sum += ex[i]; }
        #pragma unroll
        for (int i = 0; i < 5; ++i) out[i] = ex[i] / sum;
    }
}

// ---------------------------------------------------------------------------
extern "C" void kernel_launch(void* const* d_in, const int* in_sizes, int n_in,
                              void* d_out, int out_size, void* d_ws, size_t ws_size,
                              hipStream_t stream)
{
    const float* x     = (const float*)d_in[0];
    const int*   ei    = (const int*)  d_in[1];
    const float* Wl    = (const float*)d_in[2];
    const float* bl    = (const float*)d_in[3];
    const float* Wr    = (const float*)d_in[4];
    const float* br    = (const float*)d_in[5];
    const float* att   = (const float*)d_in[6];
    const float* bias1 = (const float*)d_in[7];
    const float* gamma = (const float*)d_in[8];
    const float* beta  = (const float*)d_in[9];
    const float* mean  = (const float*)d_in[10];
    const float* var   = (const float*)d_in[11];
    const float* Wc    = (const float*)d_in[12];
    const float* bc    = (const float*)d_in[13];

    const int n    = in_sizes[0] / 128;
    const int nE   = in_sizes[1] / 2;
    const int nTot = nE + n;

    unsigned char* XLq = (unsigned char*)d_ws;                       // n*128 fp8
    unsigned char* XRq = XLq + (size_t)n * 128;                      // n*128 fp8
    unsigned short* Whf = (unsigned short*)(XRq + (size_t)n * 128);  // 32768 bf16
    float* bh    = (float*)(Whf + 32768);                            // 256
    float* wbuf  = bh + 256;                                         // nTot
    float* denom = wbuf + nTot;                                      // n   } zeroed
    float* csrc  = denom + n;                                        // n   } by prep
    float* S     = csrc + n;                                         // 128 }
    unsigned int* counter = (unsigned int*)(S + 128);                // 1   }
    const int nz = 2 * n + 128 + 1;

    prep<<<512, 256, 0, stream>>>(Wl, bl, Wr, br, Whf, bh, denom, nz);

    const int ntiles = (n + GBM - 1) / GBM;
    gemm_mfma<<<ntiles, 256, 0, stream>>>(x, Whf, bh, XLq, XRq, n);

    edge_logits<<<2048, 256, 0, stream>>>(XLq, XRq, ei, att, wbuf, denom, nE, nTot);

    edge_coeff<<<2048, 256, 0, stream>>>(ei, wbuf, denom, csrc, nE, nTot);

    wsum_fin<<<512, 256, 0, stream>>>(XLq, csrc, S, counter, n,
                                      bias1, gamma, beta, mean, var, Wc, bc,
                                      (float*)d_out);
}